// Round 9
// baseline (1398.056 us; speedup 1.0000x reference)
//
#include <hip/hip_runtime.h>
#include <hip/hip_bf16.h>
#include <math.h>

// ---------------------------------------------------------------------------
// GNN_72103910966081: 4-layer LEConv GNN, N=50000, E=600000, D=128.
// Round 22: (a) revert gemmGrid to 512 — R21's grid=nTiles regressed +5us
// per GEMM (782 blocks re-run the 98KB weight preamble; persistent 2-tile
// loop amortizes it better than tile balance saves). (b) fuse aggregate_out
// + gather_out into one dispatch via done-counter handshake (both 0-LDS;
// 196 spinners << 2048 resident slots -> deadlock-free by capacity, not
// dispatch order; same fence+atomic pattern as the working fused scan).
// ---------------------------------------------------------------------------

typedef _Float16 f16x8 __attribute__((ext_vector_type(8)));
typedef _Float16 f16x4 __attribute__((ext_vector_type(4)));
typedef float f32x4 __attribute__((ext_vector_type(4)));

#define LSTRIDE 136   // halves per LDS row: 128 + 8 (16B-aligned, breaks 2^k banks)
#define CS_BLOCKS 512
#define WFIX 8388608.0f        // 2^23 fixed-point scale for packed wsum

// ===================== prep: zero only (tiny) =====================

__global__ __launch_bounds__(256) void prep_zero_kernel(
    int N, unsigned long long* __restrict__ degw, int* __restrict__ counter)
{
    int idx = blockIdx.x * 256 + threadIdx.x;     // 128 blocks -> 32768 threads
    for (int i = idx; i < N; i += 128 * 256) degw[i] = 0ULL;
    if (idx == 0) { counter[0] = 0; counter[64] = 0; counter[128] = 0; }
}

// ===================== colstats + wconvert + hist (co-scheduled) ===========
// blocks [0,512): colstats; [512,896): weight convert; [896,896+eBlocks): hist.
// colstats first (streams, occupies CUs), hist backfills (atomic-latency).

__global__ __launch_bounds__(256) void hist_cs_kernel(
    const int* __restrict__ dst, const float* __restrict__ ew,
    unsigned long long* __restrict__ degw, int* __restrict__ rank, int E,
    const float* __restrict__ x, int N,
    float* __restrict__ ps, float* __restrict__ pss,
    const float* __restrict__ W1a, const float* __restrict__ W2a,
    const float* __restrict__ W3a, _Float16* __restrict__ Wta,
    const float* __restrict__ W1b, const float* __restrict__ W2b,
    const float* __restrict__ W3b, _Float16* __restrict__ Wtb)
{
    int bid = blockIdx.x;
    int t = threadIdx.x;

    if (bid >= CS_BLOCKS + 384) {
        // ---- packed histogram ----
        int e = (bid - CS_BLOCKS - 384) * 256 + t;
        if (e < E) {
            int d = dst[e];
            unsigned int wf = __float2uint_rn(ew[e] * WFIX);
            unsigned long long old =
                atomicAdd(&degw[d], (1ULL << 32) | (unsigned long long)wf);
            rank[e] = (int)(old >> 32);
        }
        return;
    }

    if (bid >= CS_BLOCKS) {
        // ---- weight convert+transpose (both sets) ----
        int idx = (bid - CS_BLOCKS) * 256 + t;      // over 2*384*128 exactly
        int set = idx >= 384 * 128;
        int id = idx - set * 384 * 128;
        int n = id >> 7, k = id & 127;
        const float* W = set ? ((n < 128) ? W1b : (n < 256) ? W2b : W3b)
                             : ((n < 128) ? W1a : (n < 256) ? W2a : W3a);
        _Float16* Wt = set ? Wtb : Wta;
        int c = n & 127;
        Wt[id] = (_Float16)W[k * 128 + c];
        return;
    }

    // ---- colstats partials ----
    __shared__ float shs[256][4];
    __shared__ float shq[256][4];
    int cb = bid;                           // 0..511
    int g = t >> 5;
    int c = t & 31;
    const float4* xv = (const float4*)x;    // row stride 32
    const int S = CS_BLOCKS * 8;            // 4096 rows
    float s0=0.f,s1=0.f,s2=0.f,s3=0.f, q0=0.f,q1=0.f,q2=0.f,q3=0.f;
    int r = cb * 8 + g;
    for (; r + 3*S < N; r += 4*S) {
        float4 v0 = xv[(size_t)r * 32 + c];
        float4 v1 = xv[(size_t)(r + S) * 32 + c];
        float4 v2 = xv[(size_t)(r + 2*S) * 32 + c];
        float4 v3 = xv[(size_t)(r + 3*S) * 32 + c];
        s0 += v0.x + v1.x + v2.x + v3.x;
        s1 += v0.y + v1.y + v2.y + v3.y;
        s2 += v0.z + v1.z + v2.z + v3.z;
        s3 += v0.w + v1.w + v2.w + v3.w;
        q0 += v0.x*v0.x + v1.x*v1.x + v2.x*v2.x + v3.x*v3.x;
        q1 += v0.y*v0.y + v1.y*v1.y + v2.y*v2.y + v3.y*v3.y;
        q2 += v0.z*v0.z + v1.z*v1.z + v2.z*v2.z + v3.z*v3.z;
        q3 += v0.w*v0.w + v1.w*v1.w + v2.w*v2.w + v3.w*v3.w;
    }
    for (; r < N; r += S) {
        float4 v = xv[(size_t)r * 32 + c];
        s0 += v.x; s1 += v.y; s2 += v.z; s3 += v.w;
        q0 += v.x*v.x; q1 += v.y*v.y; q2 += v.z*v.z; q3 += v.w*v.w;
    }
    shs[t][0]=s0; shs[t][1]=s1; shs[t][2]=s2; shs[t][3]=s3;
    shq[t][0]=q0; shq[t][1]=q1; shq[t][2]=q2; shq[t][3]=q3;
    __syncthreads();
    if (t < 32) {
        float S4[4] = {0,0,0,0}, Q4[4] = {0,0,0,0};
        #pragma unroll
        for (int gg = 0; gg < 8; ++gg) {
            #pragma unroll
            for (int i = 0; i < 4; ++i) {
                S4[i] += shs[t + 32*gg][i];
                Q4[i] += shq[t + 32*gg][i];
            }
        }
        #pragma unroll
        for (int i = 0; i < 4; ++i) {
            ps [cb * 128 + t*4 + i] = S4[i];
            pss[cb * 128 + t*4 + i] = Q4[i];
        }
    }
}

// ===================== scan + stats-reduce (co-scheduled) ==================
// blocks [0,nb): fused scan (ticket among nb blocks, co-resident, no deadlock)
// blocks [nb, nb+128): column-stats reduction (needs only ps/pss).

__global__ __launch_bounds__(256) void scan_stats_kernel(
    const unsigned long long* __restrict__ degw, int N,
    float* __restrict__ wsum, int* __restrict__ rowptr, int E,
    int* __restrict__ partial, int* __restrict__ counter, int nb,
    const float* __restrict__ ps, const float* __restrict__ pss,
    float* __restrict__ mean, float* __restrict__ rstd)
{
    int bid = blockIdx.x;
    int t = threadIdx.x;

    if (bid >= nb) {
        // ---- stats reduce: one feature per block ----
        __shared__ float sh1[256], sh2[256];
        int f = bid - nb;                   // 0..127
        int r0 = t * 2;                     // CS_BLOCKS = 512 = 256*2
        float s1 = ps [(size_t)r0 * 128 + f] + ps [(size_t)(r0 + 1) * 128 + f];
        float s2 = pss[(size_t)r0 * 128 + f] + pss[(size_t)(r0 + 1) * 128 + f];
        sh1[t] = s1; sh2[t] = s2; __syncthreads();
        for (int off = 128; off > 0; off >>= 1) {
            if (t < off) { sh1[t] += sh1[t + off]; sh2[t] += sh2[t + off]; }
            __syncthreads();
        }
        if (t == 0) {
            float sum = sh1[0], sumsq = sh2[0];
            float m = sum / (float)N;
            float var = (sumsq - sum * sum / (float)N) / (float)(N - 1);  // ddof=1
            var = fmaxf(var, 0.f);
            mean[f] = m;
            rstd[f] = 1.f / (sqrtf(var) + 1e-6f);
        }
        return;
    }

    // ---- fused scan ----
    __shared__ int sh[256];
    __shared__ int lastFlag;
    __shared__ int blockOff;
    int base = bid * 1024 + t * 4;
    int v[4]; int s = 0;
    #pragma unroll
    for (int i = 0; i < 4; ++i) {
        int idx = base + i;
        if (idx < N) {
            unsigned long long w = degw[idx];
            v[i] = (int)(w >> 32);
            wsum[idx] = (float)(unsigned int)w * (1.0f / WFIX);
        } else v[i] = 0;
        s += v[i];
    }
    sh[t] = s; __syncthreads();
    for (int off = 1; off < 256; off <<= 1) {      // inclusive scan
        int x = sh[t];
        if (t >= off) x += sh[t - off];
        __syncthreads();
        sh[t] = x;
        __syncthreads();
    }
    if (t == 0) {
        atomicExch(&partial[bid], sh[255]);  // publish block total
        __threadfence();
        int tk = atomicAdd(&counter[0], 1);
        lastFlag = (tk == nb - 1) ? 1 : 0;
    }
    __syncthreads();
    if (lastFlag) {
        if (t < 64) {
            __threadfence();
            int o = (t < nb) ? atomicAdd(&partial[t], 0) : 0;   // nb <= 64
            int vv = o;
            #pragma unroll
            for (int off = 1; off < 64; off <<= 1) {
                int u = __shfl_up(vv, off, 64);
                if (t >= off) vv += u;
            }
            if (t < nb) atomicExch(&partial[t], vv - o);        // exclusive
        }
        __syncthreads();
        if (t == 0) { __threadfence(); atomicExch(&counter[64], 1); }
    }
    if (t == 0) {
        while (atomicAdd(&counter[64], 0) == 0) {}
        __threadfence();
        blockOff = atomicAdd(&partial[bid], 0);
    }
    __syncthreads();
    int off0 = blockOff + ((t > 0) ? sh[t - 1] : 0);
    #pragma unroll
    for (int i = 0; i < 4; ++i) {
        int idx = base + i;
        if (idx < N) { rowptr[idx] = off0; off0 += v[i]; }
    }
    if (bid == 0 && t == 0) rowptr[N] = E;
}

// ===================== csr_fill + GEMM layer-1 (co-scheduled) ==============
// blocks [0,eBlocks): CSR fill (light, pipelines under the GEMM);
// blocks [eBlocks, eBlocks+512): persistent MFMA GEMM w/ fused standardize.

__global__ __launch_bounds__(256, 2) void fill_gemm1_kernel(
    const int* __restrict__ src, const int* __restrict__ dst,
    const float* __restrict__ ew, const int* __restrict__ rowptr,
    const int* __restrict__ rank, int2* __restrict__ csr, int E, int eBlocks,
    const float* __restrict__ x,
    const float* __restrict__ meanp, const float* __restrict__ rstdp,
    int N, int nTiles, int gemmGrid,
    const _Float16* __restrict__ Wt,
    const float* __restrict__ b1,
    const float* __restrict__ b3,
    const float* __restrict__ wsum,
    _Float16* __restrict__ out_a, _Float16* __restrict__ out_d)
{
    __shared__ _Float16 ldsS[64 * LSTRIDE];
    __shared__ _Float16 lds_a[64 * LSTRIDE];
    __shared__ _Float16 lds_d[64 * LSTRIDE];

    int bid = blockIdx.x;
    int t = threadIdx.x;

    if (bid < eBlocks) {
        // ---- CSR fill (no atomics) ----
        int e = bid * 256 + t;
        if (e < E) {
            int d = dst[e];
            int pos = rowptr[d] + rank[e];
            csr[pos] = make_int2(src[e], __float_as_int(ew[e]));
        }
        return;
    }

    // ---- GEMM with fused standardization (persistent over tiles) ----
    int wave = t >> 6;
    int lane = t & 63;
    int quad = lane >> 4;
    int c16  = lane & 15;

    const f16x8* wv = (const f16x8*)Wt;
    int ntl[6] = {2*wave, 2*wave+1, 8+2*wave, 9+2*wave, 16+2*wave, 17+2*wave};
    f16x8 bfrag[6][4];
    #pragma unroll
    for (int j = 0; j < 6; ++j) {
        int nrow = ntl[j] * 16 + c16;
        #pragma unroll
        for (int s = 0; s < 4; ++s)
            bfrag[j][s] = wv[(size_t)nrow * 16 + s * 4 + quad];
    }
    float bb1[2], bb3[2];
    #pragma unroll
    for (int j = 0; j < 2; ++j) {
        int col = (2*wave + j) * 16 + c16;
        bb1[j] = b1[col];
        bb3[j] = b3[col];
    }

    int c4 = t & 31;
    float4 mu = ((const float4*)meanp)[c4];
    float4 rs = ((const float4*)rstdp)[c4];

    const float4* xv = (const float4*)x;   // row stride 32 float4
    f16x8* oa = (f16x8*)out_a;
    f16x8* od = (f16x8*)out_d;

    for (int tile = bid - eBlocks; tile < nTiles; tile += gemmGrid) {
        int row0 = tile * 64;

        #pragma unroll
        for (int i = 0; i < 8; ++i) {
            int idx = i * 256 + t;        // 0..2047
            int row = idx >> 5;           // 0..63
            int grow = row0 + row;
            if (grow >= N) grow = N - 1;
            float4 v = xv[(size_t)grow * 32 + c4];
            f16x4 o;
            o.x = (_Float16)((v.x - mu.x) * rs.x);
            o.y = (_Float16)((v.y - mu.y) * rs.y);
            o.z = (_Float16)((v.z - mu.z) * rs.z);
            o.w = (_Float16)((v.w - mu.w) * rs.w);
            *(f16x4*)&ldsS[row * LSTRIDE + c4 * 4] = o;
        }
        __syncthreads();

        #pragma unroll
        for (int r = 0; r < 4; ++r) {
            f16x8 afrag[4];
            #pragma unroll
            for (int s = 0; s < 4; ++s)
                afrag[s] = *(const f16x8*)&ldsS[(r*16 + c16) * LSTRIDE + (s*4 + quad) * 8];

            f32x4 acc[6];
            #pragma unroll
            for (int j = 0; j < 6; ++j) acc[j] = (f32x4){0.f, 0.f, 0.f, 0.f};
            #pragma unroll
            for (int s = 0; s < 4; ++s) {
                #pragma unroll
                for (int j = 0; j < 6; ++j)
                    acc[j] = __builtin_amdgcn_mfma_f32_16x16x32_f16(afrag[s], bfrag[j][s], acc[j], 0, 0, 0);
            }

            float wsv[4];
            #pragma unroll
            for (int reg = 0; reg < 4; ++reg) {
                int gr = row0 + r*16 + quad*4 + reg;
                wsv[reg] = wsum[(gr < N) ? gr : (N - 1)];
            }
            #pragma unroll
            for (int j = 0; j < 2; ++j) {
                int col = (2*wave + j) * 16 + c16;
                #pragma unroll
                for (int reg = 0; reg < 4; ++reg) {
                    int lr = r*16 + quad*4 + reg;
                    lds_a[lr * LSTRIDE + col] = (_Float16)(acc[j][reg] + bb1[j]);
                    lds_d[lr * LSTRIDE + col] =
                        (_Float16)(acc[4+j][reg] + bb3[j] - wsv[reg] * acc[2+j][reg]);
                }
            }
        }
        __syncthreads();

        #pragma unroll
        for (int i = 0; i < 4; ++i) {
            int idx = i * 256 + t;
            int row = idx >> 4;
            int c8  = idx & 15;
            int grow = row0 + row;
            if (grow < N) {
                f16x8 va = *(const f16x8*)&lds_a[row * LSTRIDE + c8 * 8];
                oa[(size_t)grow * 16 + c8] = va;
                f16x8 vd = *(const f16x8*)&lds_d[row * LSTRIDE + c8 * 8];
                od[(size_t)grow * 16 + c8] = vd;
            }
        }
        __syncthreads();
    }
}

// ===================== MFMA fused GEMM (layers 2..3, fp16 input) ===========

__global__ __launch_bounds__(256, 2) void gemm_mfma_kernel(
    const _Float16* __restrict__ h, int N, int nTiles,
    const _Float16* __restrict__ Wt,
    const float* __restrict__ b1,
    const float* __restrict__ b3,
    const float* __restrict__ wsum,
    _Float16* __restrict__ out_a, _Float16* __restrict__ out_d)
{
    __shared__ _Float16 ldsS[64 * LSTRIDE];
    __shared__ _Float16 lds_a[64 * LSTRIDE];
    __shared__ _Float16 lds_d[64 * LSTRIDE];

    int t = threadIdx.x;
    int wave = t >> 6;
    int lane = t & 63;
    int quad = lane >> 4;
    int c16  = lane & 15;

    const f16x8* wv = (const f16x8*)Wt;
    int ntl[6] = {2*wave, 2*wave+1, 8+2*wave, 9+2*wave, 16+2*wave, 17+2*wave};
    f16x8 bfrag[6][4];
    #pragma unroll
    for (int j = 0; j < 6; ++j) {
        int nrow = ntl[j] * 16 + c16;
        #pragma unroll
        for (int s = 0; s < 4; ++s)
            bfrag[j][s] = wv[(size_t)nrow * 16 + s * 4 + quad];
    }
    float bb1[2], bb3[2];
    #pragma unroll
    for (int j = 0; j < 2; ++j) {
        int col = (2*wave + j) * 16 + c16;
        bb1[j] = b1[col];
        bb3[j] = b3[col];
    }

    const f16x8* hv = (const f16x8*)h;
    f16x8* oa = (f16x8*)out_a;
    f16x8* od = (f16x8*)out_d;

    for (int tile = blockIdx.x; tile < nTiles; tile += gridDim.x) {
        int row0 = tile * 64;

        #pragma unroll
        for (int i = 0; i < 4; ++i) {
            int idx = i * 256 + t;
            int row = idx >> 4;
            int chunk = idx & 15;
            int grow = row0 + row;
            if (grow >= N) grow = N - 1;
            *(f16x8*)&ldsS[row * LSTRIDE + chunk * 8] = hv[(size_t)grow * 16 + chunk];
        }
        __syncthreads();

        #pragma unroll
        for (int r = 0; r < 4; ++r) {
            f16x8 afrag[4];
            #pragma unroll
            for (int s = 0; s < 4; ++s)
                afrag[s] = *(const f16x8*)&ldsS[(r*16 + c16) * LSTRIDE + (s*4 + quad) * 8];

            f32x4 acc[6];
            #pragma unroll
            for (int j = 0; j < 6; ++j) acc[j] = (f32x4){0.f, 0.f, 0.f, 0.f};
            #pragma unroll
            for (int s = 0; s < 4; ++s) {
                #pragma unroll
                for (int j = 0; j < 6; ++j)
                    acc[j] = __builtin_amdgcn_mfma_f32_16x16x32_f16(afrag[s], bfrag[j][s], acc[j], 0, 0, 0);
            }

            float wsv[4];
            #pragma unroll
            for (int reg = 0; reg < 4; ++reg) {
                int gr = row0 + r*16 + quad*4 + reg;
                wsv[reg] = wsum[(gr < N) ? gr : (N - 1)];
            }
            #pragma unroll
            for (int j = 0; j < 2; ++j) {
                int col = (2*wave + j) * 16 + c16;
                #pragma unroll
                for (int reg = 0; reg < 4; ++reg) {
                    int lr = r*16 + quad*4 + reg;
                    lds_a[lr * LSTRIDE + col] = (_Float16)(acc[j][reg] + bb1[j]);
                    lds_d[lr * LSTRIDE + col] =
                        (_Float16)(acc[4+j][reg] + bb3[j] - wsv[reg] * acc[2+j][reg]);
                }
            }
        }
        __syncthreads();

        #pragma unroll
        for (int i = 0; i < 4; ++i) {
            int idx = i * 256 + t;
            int row = idx >> 4;
            int c8  = idx & 15;
            int grow = row0 + row;
            if (grow < N) {
                f16x8 va = *(const f16x8*)&lds_a[row * LSTRIDE + c8 * 8];
                oa[(size_t)grow * 16 + c8] = va;
                f16x8 vd = *(const f16x8*)&lds_d[row * LSTRIDE + c8 * 8];
                od[(size_t)grow * 16 + c8] = vd;
            }
        }
        __syncthreads();
    }
}

// ===================== fused gather + LN + leaky (mid layers) ==============

__global__ __launch_bounds__(256) void aggregate_ln_kernel(
    const int* __restrict__ rowptr, const int2* __restrict__ csr,
    const _Float16* __restrict__ a, const _Float16* __restrict__ d,
    const float* __restrict__ g, const float* __restrict__ beta,
    _Float16* __restrict__ out, int N)
{
    int wave = threadIdx.x >> 6;
    int lane = threadIdx.x & 63;
    int grp  = lane >> 4;        // 0..3: edge group
    int l    = lane & 15;        // feature chunk: cols 8l..8l+7
    int node = blockIdx.x * 4 + wave;
    if (node >= N) return;
    int b = rowptr[node], en = rowptr[node + 1];
    int deg = en - b;

    const f16x8* av = (const f16x8*)a;   // row stride 16 chunks
    f16x8 dv = ((const f16x8*)d)[(size_t)node * 16 + l];   // hoisted
    float acc[8] = {0,0,0,0,0,0,0,0};

    int nk = (deg + 3) >> 2;             // edge e = b + k*4 + grp
    int k = 0;
    for (; k + 4 <= nk; k += 4) {        // 16 edge-rows in flight
        int2 p[4];
        #pragma unroll
        for (int j = 0; j < 4; ++j) {
            int idx = b + (k + j) * 4 + grp;
            int idc = (idx < en) ? idx : b;
            p[j] = csr[idc];
            if (idx >= en) p[j].y = 0;
        }
        f16x8 v[4];
        #pragma unroll
        for (int j = 0; j < 4; ++j)
            v[j] = av[(size_t)p[j].x * 16 + l];
        #pragma unroll
        for (int j = 0; j < 4; ++j) {
            float w = __int_as_float(p[j].y);
            #pragma unroll
            for (int i = 0; i < 8; ++i) acc[i] += w * (float)v[j][i];
        }
    }
    if (k < nk) {                        // predicated batch tail (1..3 live k)
        int2 p[4];
        #pragma unroll
        for (int j = 0; j < 4; ++j) {
            int idx = b + (k + j) * 4 + grp;
            int idc = (idx < en) ? idx : b;
            p[j] = csr[idc];
            if (idx >= en) p[j].y = 0;
        }
        f16x8 v[4];
        #pragma unroll
        for (int j = 0; j < 4; ++j)
            v[j] = av[(size_t)p[j].x * 16 + l];
        #pragma unroll
        for (int j = 0; j < 4; ++j) {
            float w = __int_as_float(p[j].y);
            #pragma unroll
            for (int i = 0; i < 8; ++i) acc[i] += w * (float)v[j][i];
        }
    }

    #pragma unroll
    for (int i = 0; i < 8; ++i) {
        acc[i] += __shfl_xor(acc[i], 16, 64);
        acc[i] += __shfl_xor(acc[i], 32, 64);
    }

    float v[8];
    float s = 0.f, ss = 0.f;
    #pragma unroll
    for (int i = 0; i < 8; ++i) {
        v[i] = acc[i] + (float)dv[i];
        s += v[i]; ss += v[i] * v[i];
    }
    #pragma unroll
    for (int off = 1; off <= 8; off <<= 1) {
        s  += __shfl_xor(s,  off, 64);
        ss += __shfl_xor(ss, off, 64);
    }
    float mean = s * (1.f / 128.f);
    float var = ss * (1.f / 128.f) - mean * mean;
    float rstd = rsqrtf(var + 1e-5f);

    const float4* gv4 = (const float4*)g;
    const float4* bv4 = (const float4*)beta;
    float4 ga = gv4[l*2], gb = gv4[l*2+1];
    float4 ba = bv4[l*2], bb = bv4[l*2+1];
    float go[8] = {ga.x,ga.y,ga.z,ga.w,gb.x,gb.y,gb.z,gb.w};
    float bo[8] = {ba.x,ba.y,ba.z,ba.w,bb.x,bb.y,bb.z,bb.w};
    f16x8 ov;
    #pragma unroll
    for (int i = 0; i < 8; ++i) {
        float o = (v[i] - mean) * rstd * go[i] + bo[i];
        o = o >= 0.f ? o : 0.1f * o;
        ov[i] = (_Float16)o;
    }
    if (grp == 0)
        ((f16x8*)out)[(size_t)node * 16 + l] = ov;
}

// ============ final aggregate + LN + output GEMV + gather + sigmoid ========
// ONE dispatch: blocks [0,nAgg) run aggregate_out; blocks [nAgg,nAgg+nOut)
// spin on a done counter (capacity-safe: 196 spinners << 2048 slots for
// 0-LDS blocks), then run the output gather + sigmoid.

__global__ __launch_bounds__(256) void aggout_gather_kernel(
    const int* __restrict__ rowptr, const int2* __restrict__ csr,
    const _Float16* __restrict__ a, const _Float16* __restrict__ d,
    const float* __restrict__ g, const float* __restrict__ beta,
    const float* __restrict__ W1o, const float* __restrict__ b1o,
    const float* __restrict__ W2o,
    const float* __restrict__ W3o, const float* __restrict__ b3o,
    const float* __restrict__ wsum,
    float* __restrict__ a1, float* __restrict__ dpart,
    float* __restrict__ out, int N, int nAgg, int* __restrict__ counter)
{
    int bid = blockIdx.x;
    int t = threadIdx.x;

    if (bid >= nAgg) {
        // ---- output gather + sigmoid (after all agg blocks signal) ----
        __shared__ int ready;
        if (t == 0) {
            while (atomicAdd(&counter[128], 0) < nAgg) {}
            __threadfence();
            ready = 1;
        }
        __syncthreads();
        (void)ready;
        int n = (bid - nAgg) * 256 + t;
        if (n >= N) return;
        int b = rowptr[n], en = rowptr[n + 1];
        float s = dpart[n];
        int e = b;
        for (; e + 4 <= en; e += 4) {
            int2 p0 = csr[e], p1 = csr[e+1], p2 = csr[e+2], p3 = csr[e+3];
            float x0 = a1[p0.x], x1 = a1[p1.x], x2 = a1[p2.x], x3 = a1[p3.x];
            s += __int_as_float(p0.y) * x0 + __int_as_float(p1.y) * x1
               + __int_as_float(p2.y) * x2 + __int_as_float(p3.y) * x3;
        }
        for (; e < en; ++e) {
            int2 p = csr[e];
            s += __int_as_float(p.y) * a1[p.x];
        }
        out[n] = 1.f / (1.f + expf(-s));
        return;
    }

    // ---- aggregate_out body (no early return; signal at end) ----
    int wave = t >> 6;
    int lane = t & 63;
    int grp  = lane >> 4;
    int l    = lane & 15;
    int node = bid * 4 + wave;

    if (node < N) {
        int b = rowptr[node], en = rowptr[node + 1];
        int deg = en - b;

        const f16x8* av = (const f16x8*)a;
        f16x8 dv = ((const f16x8*)d)[(size_t)node * 16 + l];   // hoisted
        float wsn = wsum[node];
        float acc[8] = {0,0,0,0,0,0,0,0};

        int nk = (deg + 3) >> 2;
        int k = 0;
        for (; k + 4 <= nk; k += 4) {
            int2 p[4];
            #pragma unroll
            for (int j = 0; j < 4; ++j) {
                int idx = b + (k + j) * 4 + grp;
                int idc = (idx < en) ? idx : b;
                p[j] = csr[idc];
                if (idx >= en) p[j].y = 0;
            }
            f16x8 v[4];
            #pragma unroll
            for (int j = 0; j < 4; ++j)
                v[j] = av[(size_t)p[j].x * 16 + l];
            #pragma unroll
            for (int j = 0; j < 4; ++j) {
                float w = __int_as_float(p[j].y);
                #pragma unroll
                for (int i = 0; i < 8; ++i) acc[i] += w * (float)v[j][i];
            }
        }
        if (k < nk) {                        // predicated batch tail
            int2 p[4];
            #pragma unroll
            for (int j = 0; j < 4; ++j) {
                int idx = b + (k + j) * 4 + grp;
                int idc = (idx < en) ? idx : b;
                p[j] = csr[idc];
                if (idx >= en) p[j].y = 0;
            }
            f16x8 v[4];
            #pragma unroll
            for (int j = 0; j < 4; ++j)
                v[j] = av[(size_t)p[j].x * 16 + l];
            #pragma unroll
            for (int j = 0; j < 4; ++j) {
                float w = __int_as_float(p[j].y);
                #pragma unroll
                for (int i = 0; i < 8; ++i) acc[i] += w * (float)v[j][i];
            }
        }

        #pragma unroll
        for (int i = 0; i < 8; ++i) {
            acc[i] += __shfl_xor(acc[i], 16, 64);
            acc[i] += __shfl_xor(acc[i], 32, 64);
        }

        float v[8];
        float s = 0.f, ss = 0.f;
        #pragma unroll
        for (int i = 0; i < 8; ++i) {
            v[i] = acc[i] + (float)dv[i];
            s += v[i]; ss += v[i] * v[i];
        }
        #pragma unroll
        for (int off = 1; off <= 8; off <<= 1) {
            s  += __shfl_xor(s,  off, 64);
            ss += __shfl_xor(ss, off, 64);
        }
        float mean = s * (1.f / 128.f);
        float var = ss * (1.f / 128.f) - mean * mean;
        float rstd = rsqrtf(var + 1e-5f);

        const float4* gv4 = (const float4*)g;
        const float4* bv4 = (const float4*)beta;
        float4 ga = gv4[l*2], gb = gv4[l*2+1];
        float4 ba = bv4[l*2], bb = bv4[l*2+1];
        float go[8] = {ga.x,ga.y,ga.z,ga.w,gb.x,gb.y,gb.z,gb.w};
        float bo[8] = {ba.x,ba.y,ba.z,ba.w,bb.x,bb.y,bb.z,bb.w};

        float ho[8];
        #pragma unroll
        for (int i = 0; i < 8; ++i) {
            float o = (v[i] - mean) * rstd * go[i] + bo[i];
            o = o >= 0.f ? o : 0.1f * o;
            ho[i] = (float)(_Float16)o;   // match two-kernel path bit-for-bit
        }

        const float4* w1v = (const float4*)W1o;
        const float4* w2v = (const float4*)W2o;
        const float4* w3v = (const float4*)W3o;
        float4 w1a = w1v[l*2], w1b = w1v[l*2+1];
        float4 w2a = w2v[l*2], w2b = w2v[l*2+1];
        float4 w3a = w3v[l*2], w3b = w3v[l*2+1];
        float s1 = ho[0]*w1a.x + ho[1]*w1a.y + ho[2]*w1a.z + ho[3]*w1a.w
                 + ho[4]*w1b.x + ho[5]*w1b.y + ho[6]*w1b.z + ho[7]*w1b.w;
        float s2 = ho[0]*w2a.x + ho[1]*w2a.y + ho[2]*w2a.z + ho[3]*w2a.w
                 + ho[4]*w2b.x + ho[5]*w2b.y + ho[6]*w2b.z + ho[7]*w2b.w;
        float s3 = ho[0]*w3a.x + ho[1]*w3a.y + ho[2]*w3a.z + ho[3]*w3a.w
                 + ho[4]*w3b.x + ho[5]*w3b.y + ho[6]*w3b.z + ho[7]*w3b.w;
        #pragma unroll
        for (int off = 1; off <= 8; off <<= 1) {
            s1 += __shfl_xor(s1, off, 64);
            s2 += __shfl_xor(s2, off, 64);
            s3 += __shfl_xor(s3, off, 64);
        }
        if (lane == 0) {
            a1[node] = s1 + b1o[0];
            dpart[node] = s3 + b3o[0] - wsn * s2;
        }
    }

    __syncthreads();
    __threadfence();
    if (t == 0) atomicAdd(&counter[128], 1);
}

// ---------------------------------------------------------------------------
extern "C" void kernel_launch(void* const* d_in, const int* in_sizes, int n_in,
                              void* d_out, int out_size, void* d_ws, size_t ws_size,
                              hipStream_t stream)
{
    const float* x     = (const float*)d_in[0];
    const float* ew    = (const float*)d_in[1];
    const float* W1_in = (const float*)d_in[2];
    const float* b1_in = (const float*)d_in[3];
    const float* W2_in = (const float*)d_in[4];
    const float* W3_in = (const float*)d_in[5];
    const float* b3_in = (const float*)d_in[6];
    const float* W1_h  = (const float*)d_in[7];
    const float* b1_h  = (const float*)d_in[8];
    const float* W2_h  = (const float*)d_in[9];
    const float* W3_h  = (const float*)d_in[10];
    const float* b3_h  = (const float*)d_in[11];
    const float* W1_o  = (const float*)d_in[12];
    const float* b1_o  = (const float*)d_in[13];
    const float* W2_o  = (const float*)d_in[14];
    const float* W3_o  = (const float*)d_in[15];
    const float* b3_o  = (const float*)d_in[16];
    const float* g1    = (const float*)d_in[17];
    const float* beta1 = (const float*)d_in[18];
    const float* g2    = (const float*)d_in[19];
    const float* beta2 = (const float*)d_in[20];
    const int*   eidx  = (const int*)d_in[21];

    const int N = in_sizes[0] / 128;
    const int E = in_sizes[1];
    const int* srcp = eidx;
    const int* dstp = eidx + E;

    // ---- workspace carve-out (256B-aligned chunks) ----
    size_t off = 0;
    auto carve = [&](size_t nbytes) -> void* {
        void* p = (char*)d_ws + off;
        off += (nbytes + 255) & ~(size_t)255;
        return p;
    };
    unsigned long long* degw = (unsigned long long*)carve((size_t)N * 8);
    int*      rank   = (int*)     carve((size_t)E * 4);
    _Float16* buf_h  = (_Float16*)carve((size_t)N * 128 * 2);
    _Float16* buf_a  = (_Float16*)carve((size_t)N * 128 * 2);
    _Float16* buf_d  = (_Float16*)carve((size_t)N * 128 * 2);
    int2*     csr    = (int2*)    carve((size_t)E * 8);
    _Float16* Wt_in  = (_Float16*)carve(384 * 128 * 2);
    _Float16* Wt_h   = (_Float16*)carve(384 * 128 * 2);
    int*      rowptr = (int*)     carve((size_t)(N + 1) * 4);
    int*      partial= (int*)     carve(256 * 4);
    int*      counter= (int*)     carve(256 * 4);
    float*    ps     = (float*)   carve((size_t)CS_BLOCKS * 128 * 4);
    float*    pss    = (float*)   carve((size_t)CS_BLOCKS * 128 * 4);
    float*    meanp  = (float*)   carve(128 * 4);
    float*    rstdp  = (float*)   carve(128 * 4);
    float*    wsum   = (float*)   carve((size_t)N * 4);
    float*    a1     = (float*)   carve((size_t)N * 4);
    float*    dpart  = (float*)   carve((size_t)N * 4);

    const int nodeWaveBlocks = (N + 3) / 4;
    const int eBlocks = (E + 255) / 256;
    const int nBlocks = (N + 255) / 256;
    const int nb = (N + 1023) / 1024;
    const int nTiles = (N + 63) / 64;
    const int gemmGrid = (nTiles < 512) ? nTiles : 512;   // proven best (R18/R21)

    // ---- 1. prep: zero degw/counters (tiny) ----
    prep_zero_kernel<<<128, 256, 0, stream>>>(N, degw, counter);

    // ---- 2. colstats + weight-convert + packed histogram (co-scheduled) ----
    hist_cs_kernel<<<CS_BLOCKS + 384 + eBlocks, 256, 0, stream>>>(
        dstp, ew, degw, rank, E, x, N, ps, pss,
        W1_in, W2_in, W3_in, Wt_in, W1_h, W2_h, W3_h, Wt_h);

    // ---- 3. fused scan + column-stats reduction (co-scheduled) ----
    scan_stats_kernel<<<nb + 128, 256, 0, stream>>>(
        degw, N, wsum, rowptr, E, partial, counter, nb,
        ps, pss, meanp, rstdp);

    // ---- 4. CSR fill + GEMM layer 1 (co-scheduled) ----
    fill_gemm1_kernel<<<eBlocks + gemmGrid, 256, 0, stream>>>(
        srcp, dstp, ew, rowptr, rank, csr, E, eBlocks,
        x, meanp, rstdp, N, nTiles, gemmGrid,
        Wt_in, b1_in, b3_in, wsum, buf_a, buf_d);

    // ---- 5. aggregate L1 ----
    aggregate_ln_kernel<<<nodeWaveBlocks, 256, 0, stream>>>(rowptr, csr, buf_a, buf_d, g1, beta1, buf_h, N);

    // ---- 6-7. layer 2 ----
    gemm_mfma_kernel<<<gemmGrid, 256, 0, stream>>>(buf_h, N, nTiles, Wt_h, b1_h, b3_h, wsum, buf_a, buf_d);
    aggregate_ln_kernel<<<nodeWaveBlocks, 256, 0, stream>>>(rowptr, csr, buf_a, buf_d, g2, beta2, buf_h, N);

    // ---- 8. layer 3 GEMM ----
    gemm_mfma_kernel<<<gemmGrid, 256, 0, stream>>>(buf_h, N, nTiles, Wt_h, b1_h, b3_h, wsum, buf_a, buf_d);

    // ---- 9. final aggregate + output GEMV + gather + sigmoid (fused) ----
    aggout_gather_kernel<<<nodeWaveBlocks + nBlocks, 256, 0, stream>>>(
        rowptr, csr, buf_a, buf_d, g2, beta2,
        W1_o, b1_o, W2_o, W3_o, b3_o, wsum, a1, dpart,
        (float*)d_out, N, nodeWaveBlocks, counter);
}

// Round 10
// 298.681 us; speedup vs baseline: 4.6808x; 4.6808x over previous
//
#include <hip/hip_runtime.h>
#include <hip/hip_bf16.h>
#include <math.h>

// ---------------------------------------------------------------------------
// GNN_72103910966081: 4-layer LEConv GNN, N=50000, E=600000, D=128.
// Round 23: PURE REVERT to R20 (299.2us, best measured). R22's spin-fusion
// of aggregate_out+gather regressed 4.7x: 196 polling blocks hammering one
// LLC atomic line serialized against 12500 signalling blocks. Ledger lesson:
// intra-dispatch co-scheduling is for INDEPENDENT work only; producer->
// consumer handshakes lose to a plain dispatch boundary. gemmGrid=512 +
// __launch_bounds__(256,2) is the proven GEMM config (R18/R21 regressions).
// ---------------------------------------------------------------------------

typedef _Float16 f16x8 __attribute__((ext_vector_type(8)));
typedef _Float16 f16x4 __attribute__((ext_vector_type(4)));
typedef float f32x4 __attribute__((ext_vector_type(4)));

#define LSTRIDE 136   // halves per LDS row: 128 + 8 (16B-aligned, breaks 2^k banks)
#define CS_BLOCKS 512
#define WFIX 8388608.0f        // 2^23 fixed-point scale for packed wsum

// ===================== prep: zero only (tiny) =====================

__global__ __launch_bounds__(256) void prep_zero_kernel(
    int N, unsigned long long* __restrict__ degw, int* __restrict__ counter)
{
    int idx = blockIdx.x * 256 + threadIdx.x;     // 128 blocks -> 32768 threads
    for (int i = idx; i < N; i += 128 * 256) degw[i] = 0ULL;
    if (idx == 0) { counter[0] = 0; counter[64] = 0; }
}

// ===================== colstats + wconvert + hist (co-scheduled) ===========
// blocks [0,512): colstats; [512,896): weight convert; [896,896+eBlocks): hist.
// colstats first (streams, occupies CUs), hist backfills (atomic-latency).

__global__ __launch_bounds__(256) void hist_cs_kernel(
    const int* __restrict__ dst, const float* __restrict__ ew,
    unsigned long long* __restrict__ degw, int* __restrict__ rank, int E,
    const float* __restrict__ x, int N,
    float* __restrict__ ps, float* __restrict__ pss,
    const float* __restrict__ W1a, const float* __restrict__ W2a,
    const float* __restrict__ W3a, _Float16* __restrict__ Wta,
    const float* __restrict__ W1b, const float* __restrict__ W2b,
    const float* __restrict__ W3b, _Float16* __restrict__ Wtb)
{
    int bid = blockIdx.x;
    int t = threadIdx.x;

    if (bid >= CS_BLOCKS + 384) {
        // ---- packed histogram ----
        int e = (bid - CS_BLOCKS - 384) * 256 + t;
        if (e < E) {
            int d = dst[e];
            unsigned int wf = __float2uint_rn(ew[e] * WFIX);
            unsigned long long old =
                atomicAdd(&degw[d], (1ULL << 32) | (unsigned long long)wf);
            rank[e] = (int)(old >> 32);
        }
        return;
    }

    if (bid >= CS_BLOCKS) {
        // ---- weight convert+transpose (both sets) ----
        int idx = (bid - CS_BLOCKS) * 256 + t;      // over 2*384*128 exactly
        int set = idx >= 384 * 128;
        int id = idx - set * 384 * 128;
        int n = id >> 7, k = id & 127;
        const float* W = set ? ((n < 128) ? W1b : (n < 256) ? W2b : W3b)
                             : ((n < 128) ? W1a : (n < 256) ? W2a : W3a);
        _Float16* Wt = set ? Wtb : Wta;
        int c = n & 127;
        Wt[id] = (_Float16)W[k * 128 + c];
        return;
    }

    // ---- colstats partials ----
    __shared__ float shs[256][4];
    __shared__ float shq[256][4];
    int cb = bid;                           // 0..511
    int g = t >> 5;
    int c = t & 31;
    const float4* xv = (const float4*)x;    // row stride 32
    const int S = CS_BLOCKS * 8;            // 4096 rows
    float s0=0.f,s1=0.f,s2=0.f,s3=0.f, q0=0.f,q1=0.f,q2=0.f,q3=0.f;
    int r = cb * 8 + g;
    for (; r + 3*S < N; r += 4*S) {
        float4 v0 = xv[(size_t)r * 32 + c];
        float4 v1 = xv[(size_t)(r + S) * 32 + c];
        float4 v2 = xv[(size_t)(r + 2*S) * 32 + c];
        float4 v3 = xv[(size_t)(r + 3*S) * 32 + c];
        s0 += v0.x + v1.x + v2.x + v3.x;
        s1 += v0.y + v1.y + v2.y + v3.y;
        s2 += v0.z + v1.z + v2.z + v3.z;
        s3 += v0.w + v1.w + v2.w + v3.w;
        q0 += v0.x*v0.x + v1.x*v1.x + v2.x*v2.x + v3.x*v3.x;
        q1 += v0.y*v0.y + v1.y*v1.y + v2.y*v2.y + v3.y*v3.y;
        q2 += v0.z*v0.z + v1.z*v1.z + v2.z*v2.z + v3.z*v3.z;
        q3 += v0.w*v0.w + v1.w*v1.w + v2.w*v2.w + v3.w*v3.w;
    }
    for (; r < N; r += S) {
        float4 v = xv[(size_t)r * 32 + c];
        s0 += v.x; s1 += v.y; s2 += v.z; s3 += v.w;
        q0 += v.x*v.x; q1 += v.y*v.y; q2 += v.z*v.z; q3 += v.w*v.w;
    }
    shs[t][0]=s0; shs[t][1]=s1; shs[t][2]=s2; shs[t][3]=s3;
    shq[t][0]=q0; shq[t][1]=q1; shq[t][2]=q2; shq[t][3]=q3;
    __syncthreads();
    if (t < 32) {
        float S4[4] = {0,0,0,0}, Q4[4] = {0,0,0,0};
        #pragma unroll
        for (int gg = 0; gg < 8; ++gg) {
            #pragma unroll
            for (int i = 0; i < 4; ++i) {
                S4[i] += shs[t + 32*gg][i];
                Q4[i] += shq[t + 32*gg][i];
            }
        }
        #pragma unroll
        for (int i = 0; i < 4; ++i) {
            ps [cb * 128 + t*4 + i] = S4[i];
            pss[cb * 128 + t*4 + i] = Q4[i];
        }
    }
}

// ===================== scan + stats-reduce (co-scheduled) ==================
// blocks [0,nb): fused scan (ticket among nb blocks, co-resident, no deadlock)
// blocks [nb, nb+128): column-stats reduction (needs only ps/pss).

__global__ __launch_bounds__(256) void scan_stats_kernel(
    const unsigned long long* __restrict__ degw, int N,
    float* __restrict__ wsum, int* __restrict__ rowptr, int E,
    int* __restrict__ partial, int* __restrict__ counter, int nb,
    const float* __restrict__ ps, const float* __restrict__ pss,
    float* __restrict__ mean, float* __restrict__ rstd)
{
    int bid = blockIdx.x;
    int t = threadIdx.x;

    if (bid >= nb) {
        // ---- stats reduce: one feature per block ----
        __shared__ float sh1[256], sh2[256];
        int f = bid - nb;                   // 0..127
        int r0 = t * 2;                     // CS_BLOCKS = 512 = 256*2
        float s1 = ps [(size_t)r0 * 128 + f] + ps [(size_t)(r0 + 1) * 128 + f];
        float s2 = pss[(size_t)r0 * 128 + f] + pss[(size_t)(r0 + 1) * 128 + f];
        sh1[t] = s1; sh2[t] = s2; __syncthreads();
        for (int off = 128; off > 0; off >>= 1) {
            if (t < off) { sh1[t] += sh1[t + off]; sh2[t] += sh2[t + off]; }
            __syncthreads();
        }
        if (t == 0) {
            float sum = sh1[0], sumsq = sh2[0];
            float m = sum / (float)N;
            float var = (sumsq - sum * sum / (float)N) / (float)(N - 1);  // ddof=1
            var = fmaxf(var, 0.f);
            mean[f] = m;
            rstd[f] = 1.f / (sqrtf(var) + 1e-6f);
        }
        return;
    }

    // ---- fused scan ----
    __shared__ int sh[256];
    __shared__ int lastFlag;
    __shared__ int blockOff;
    int base = bid * 1024 + t * 4;
    int v[4]; int s = 0;
    #pragma unroll
    for (int i = 0; i < 4; ++i) {
        int idx = base + i;
        if (idx < N) {
            unsigned long long w = degw[idx];
            v[i] = (int)(w >> 32);
            wsum[idx] = (float)(unsigned int)w * (1.0f / WFIX);
        } else v[i] = 0;
        s += v[i];
    }
    sh[t] = s; __syncthreads();
    for (int off = 1; off < 256; off <<= 1) {      // inclusive scan
        int x = sh[t];
        if (t >= off) x += sh[t - off];
        __syncthreads();
        sh[t] = x;
        __syncthreads();
    }
    if (t == 0) {
        atomicExch(&partial[bid], sh[255]);  // publish block total
        __threadfence();
        int tk = atomicAdd(&counter[0], 1);
        lastFlag = (tk == nb - 1) ? 1 : 0;
    }
    __syncthreads();
    if (lastFlag) {
        if (t < 64) {
            __threadfence();
            int o = (t < nb) ? atomicAdd(&partial[t], 0) : 0;   // nb <= 64
            int vv = o;
            #pragma unroll
            for (int off = 1; off < 64; off <<= 1) {
                int u = __shfl_up(vv, off, 64);
                if (t >= off) vv += u;
            }
            if (t < nb) atomicExch(&partial[t], vv - o);        // exclusive
        }
        __syncthreads();
        if (t == 0) { __threadfence(); atomicExch(&counter[64], 1); }
    }
    if (t == 0) {
        while (atomicAdd(&counter[64], 0) == 0) {}
        __threadfence();
        blockOff = atomicAdd(&partial[bid], 0);
    }
    __syncthreads();
    int off0 = blockOff + ((t > 0) ? sh[t - 1] : 0);
    #pragma unroll
    for (int i = 0; i < 4; ++i) {
        int idx = base + i;
        if (idx < N) { rowptr[idx] = off0; off0 += v[i]; }
    }
    if (bid == 0 && t == 0) rowptr[N] = E;
}

// ===================== csr_fill + GEMM layer-1 (co-scheduled) ==============
// blocks [0,eBlocks): CSR fill (light, pipelines under the GEMM);
// blocks [eBlocks, eBlocks+512): persistent MFMA GEMM w/ fused standardize.

__global__ __launch_bounds__(256, 2) void fill_gemm1_kernel(
    const int* __restrict__ src, const int* __restrict__ dst,
    const float* __restrict__ ew, const int* __restrict__ rowptr,
    const int* __restrict__ rank, int2* __restrict__ csr, int E, int eBlocks,
    const float* __restrict__ x,
    const float* __restrict__ meanp, const float* __restrict__ rstdp,
    int N, int nTiles, int gemmGrid,
    const _Float16* __restrict__ Wt,
    const float* __restrict__ b1,
    const float* __restrict__ b3,
    const float* __restrict__ wsum,
    _Float16* __restrict__ out_a, _Float16* __restrict__ out_d)
{
    __shared__ _Float16 ldsS[64 * LSTRIDE];
    __shared__ _Float16 lds_a[64 * LSTRIDE];
    __shared__ _Float16 lds_d[64 * LSTRIDE];

    int bid = blockIdx.x;
    int t = threadIdx.x;

    if (bid < eBlocks) {
        // ---- CSR fill (no atomics) ----
        int e = bid * 256 + t;
        if (e < E) {
            int d = dst[e];
            int pos = rowptr[d] + rank[e];
            csr[pos] = make_int2(src[e], __float_as_int(ew[e]));
        }
        return;
    }

    // ---- GEMM with fused standardization (persistent over tiles) ----
    int wave = t >> 6;
    int lane = t & 63;
    int quad = lane >> 4;
    int c16  = lane & 15;

    const f16x8* wv = (const f16x8*)Wt;
    int ntl[6] = {2*wave, 2*wave+1, 8+2*wave, 9+2*wave, 16+2*wave, 17+2*wave};
    f16x8 bfrag[6][4];
    #pragma unroll
    for (int j = 0; j < 6; ++j) {
        int nrow = ntl[j] * 16 + c16;
        #pragma unroll
        for (int s = 0; s < 4; ++s)
            bfrag[j][s] = wv[(size_t)nrow * 16 + s * 4 + quad];
    }
    float bb1[2], bb3[2];
    #pragma unroll
    for (int j = 0; j < 2; ++j) {
        int col = (2*wave + j) * 16 + c16;
        bb1[j] = b1[col];
        bb3[j] = b3[col];
    }

    int c4 = t & 31;
    float4 mu = ((const float4*)meanp)[c4];
    float4 rs = ((const float4*)rstdp)[c4];

    const float4* xv = (const float4*)x;   // row stride 32 float4
    f16x8* oa = (f16x8*)out_a;
    f16x8* od = (f16x8*)out_d;

    for (int tile = bid - eBlocks; tile < nTiles; tile += gemmGrid) {
        int row0 = tile * 64;

        #pragma unroll
        for (int i = 0; i < 8; ++i) {
            int idx = i * 256 + t;        // 0..2047
            int row = idx >> 5;           // 0..63
            int grow = row0 + row;
            if (grow >= N) grow = N - 1;
            float4 v = xv[(size_t)grow * 32 + c4];
            f16x4 o;
            o.x = (_Float16)((v.x - mu.x) * rs.x);
            o.y = (_Float16)((v.y - mu.y) * rs.y);
            o.z = (_Float16)((v.z - mu.z) * rs.z);
            o.w = (_Float16)((v.w - mu.w) * rs.w);
            *(f16x4*)&ldsS[row * LSTRIDE + c4 * 4] = o;
        }
        __syncthreads();

        #pragma unroll
        for (int r = 0; r < 4; ++r) {
            f16x8 afrag[4];
            #pragma unroll
            for (int s = 0; s < 4; ++s)
                afrag[s] = *(const f16x8*)&ldsS[(r*16 + c16) * LSTRIDE + (s*4 + quad) * 8];

            f32x4 acc[6];
            #pragma unroll
            for (int j = 0; j < 6; ++j) acc[j] = (f32x4){0.f, 0.f, 0.f, 0.f};
            #pragma unroll
            for (int s = 0; s < 4; ++s) {
                #pragma unroll
                for (int j = 0; j < 6; ++j)
                    acc[j] = __builtin_amdgcn_mfma_f32_16x16x32_f16(afrag[s], bfrag[j][s], acc[j], 0, 0, 0);
            }

            float wsv[4];
            #pragma unroll
            for (int reg = 0; reg < 4; ++reg) {
                int gr = row0 + r*16 + quad*4 + reg;
                wsv[reg] = wsum[(gr < N) ? gr : (N - 1)];
            }
            #pragma unroll
            for (int j = 0; j < 2; ++j) {
                int col = (2*wave + j) * 16 + c16;
                #pragma unroll
                for (int reg = 0; reg < 4; ++reg) {
                    int lr = r*16 + quad*4 + reg;
                    lds_a[lr * LSTRIDE + col] = (_Float16)(acc[j][reg] + bb1[j]);
                    lds_d[lr * LSTRIDE + col] =
                        (_Float16)(acc[4+j][reg] + bb3[j] - wsv[reg] * acc[2+j][reg]);
                }
            }
        }
        __syncthreads();

        #pragma unroll
        for (int i = 0; i < 4; ++i) {
            int idx = i * 256 + t;
            int row = idx >> 4;
            int c8  = idx & 15;
            int grow = row0 + row;
            if (grow < N) {
                f16x8 va = *(const f16x8*)&lds_a[row * LSTRIDE + c8 * 8];
                oa[(size_t)grow * 16 + c8] = va;
                f16x8 vd = *(const f16x8*)&lds_d[row * LSTRIDE + c8 * 8];
                od[(size_t)grow * 16 + c8] = vd;
            }
        }
        __syncthreads();
    }
}

// ===================== MFMA fused GEMM (layers 2..3, fp16 input) ===========

__global__ __launch_bounds__(256, 2) void gemm_mfma_kernel(
    const _Float16* __restrict__ h, int N, int nTiles,
    const _Float16* __restrict__ Wt,
    const float* __restrict__ b1,
    const float* __restrict__ b3,
    const float* __restrict__ wsum,
    _Float16* __restrict__ out_a, _Float16* __restrict__ out_d)
{
    __shared__ _Float16 ldsS[64 * LSTRIDE];
    __shared__ _Float16 lds_a[64 * LSTRIDE];
    __shared__ _Float16 lds_d[64 * LSTRIDE];

    int t = threadIdx.x;
    int wave = t >> 6;
    int lane = t & 63;
    int quad = lane >> 4;
    int c16  = lane & 15;

    const f16x8* wv = (const f16x8*)Wt;
    int ntl[6] = {2*wave, 2*wave+1, 8+2*wave, 9+2*wave, 16+2*wave, 17+2*wave};
    f16x8 bfrag[6][4];
    #pragma unroll
    for (int j = 0; j < 6; ++j) {
        int nrow = ntl[j] * 16 + c16;
        #pragma unroll
        for (int s = 0; s < 4; ++s)
            bfrag[j][s] = wv[(size_t)nrow * 16 + s * 4 + quad];
    }
    float bb1[2], bb3[2];
    #pragma unroll
    for (int j = 0; j < 2; ++j) {
        int col = (2*wave + j) * 16 + c16;
        bb1[j] = b1[col];
        bb3[j] = b3[col];
    }

    const f16x8* hv = (const f16x8*)h;
    f16x8* oa = (f16x8*)out_a;
    f16x8* od = (f16x8*)out_d;

    for (int tile = blockIdx.x; tile < nTiles; tile += gridDim.x) {
        int row0 = tile * 64;

        #pragma unroll
        for (int i = 0; i < 4; ++i) {
            int idx = i * 256 + t;
            int row = idx >> 4;
            int chunk = idx & 15;
            int grow = row0 + row;
            if (grow >= N) grow = N - 1;
            *(f16x8*)&ldsS[row * LSTRIDE + chunk * 8] = hv[(size_t)grow * 16 + chunk];
        }
        __syncthreads();

        #pragma unroll
        for (int r = 0; r < 4; ++r) {
            f16x8 afrag[4];
            #pragma unroll
            for (int s = 0; s < 4; ++s)
                afrag[s] = *(const f16x8*)&ldsS[(r*16 + c16) * LSTRIDE + (s*4 + quad) * 8];

            f32x4 acc[6];
            #pragma unroll
            for (int j = 0; j < 6; ++j) acc[j] = (f32x4){0.f, 0.f, 0.f, 0.f};
            #pragma unroll
            for (int s = 0; s < 4; ++s) {
                #pragma unroll
                for (int j = 0; j < 6; ++j)
                    acc[j] = __builtin_amdgcn_mfma_f32_16x16x32_f16(afrag[s], bfrag[j][s], acc[j], 0, 0, 0);
            }

            float wsv[4];
            #pragma unroll
            for (int reg = 0; reg < 4; ++reg) {
                int gr = row0 + r*16 + quad*4 + reg;
                wsv[reg] = wsum[(gr < N) ? gr : (N - 1)];
            }
            #pragma unroll
            for (int j = 0; j < 2; ++j) {
                int col = (2*wave + j) * 16 + c16;
                #pragma unroll
                for (int reg = 0; reg < 4; ++reg) {
                    int lr = r*16 + quad*4 + reg;
                    lds_a[lr * LSTRIDE + col] = (_Float16)(acc[j][reg] + bb1[j]);
                    lds_d[lr * LSTRIDE + col] =
                        (_Float16)(acc[4+j][reg] + bb3[j] - wsv[reg] * acc[2+j][reg]);
                }
            }
        }
        __syncthreads();

        #pragma unroll
        for (int i = 0; i < 4; ++i) {
            int idx = i * 256 + t;
            int row = idx >> 4;
            int c8  = idx & 15;
            int grow = row0 + row;
            if (grow < N) {
                f16x8 va = *(const f16x8*)&lds_a[row * LSTRIDE + c8 * 8];
                oa[(size_t)grow * 16 + c8] = va;
                f16x8 vd = *(const f16x8*)&lds_d[row * LSTRIDE + c8 * 8];
                od[(size_t)grow * 16 + c8] = vd;
            }
        }
        __syncthreads();
    }
}

// ===================== fused gather + LN + leaky (mid layers) ==============

__global__ __launch_bounds__(256) void aggregate_ln_kernel(
    const int* __restrict__ rowptr, const int2* __restrict__ csr,
    const _Float16* __restrict__ a, const _Float16* __restrict__ d,
    const float* __restrict__ g, const float* __restrict__ beta,
    _Float16* __restrict__ out, int N)
{
    int wave = threadIdx.x >> 6;
    int lane = threadIdx.x & 63;
    int grp  = lane >> 4;        // 0..3: edge group
    int l    = lane & 15;        // feature chunk: cols 8l..8l+7
    int node = blockIdx.x * 4 + wave;
    if (node >= N) return;
    int b = rowptr[node], en = rowptr[node + 1];
    int deg = en - b;

    const f16x8* av = (const f16x8*)a;   // row stride 16 chunks
    f16x8 dv = ((const f16x8*)d)[(size_t)node * 16 + l];   // hoisted
    float acc[8] = {0,0,0,0,0,0,0,0};

    int nk = (deg + 3) >> 2;             // edge e = b + k*4 + grp
    int k = 0;
    for (; k + 4 <= nk; k += 4) {        // 16 edge-rows in flight
        int2 p[4];
        #pragma unroll
        for (int j = 0; j < 4; ++j) {
            int idx = b + (k + j) * 4 + grp;
            int idc = (idx < en) ? idx : b;
            p[j] = csr[idc];
            if (idx >= en) p[j].y = 0;
        }
        f16x8 v[4];
        #pragma unroll
        for (int j = 0; j < 4; ++j)
            v[j] = av[(size_t)p[j].x * 16 + l];
        #pragma unroll
        for (int j = 0; j < 4; ++j) {
            float w = __int_as_float(p[j].y);
            #pragma unroll
            for (int i = 0; i < 8; ++i) acc[i] += w * (float)v[j][i];
        }
    }
    if (k < nk) {                        // predicated batch tail (1..3 live k)
        int2 p[4];
        #pragma unroll
        for (int j = 0; j < 4; ++j) {
            int idx = b + (k + j) * 4 + grp;
            int idc = (idx < en) ? idx : b;
            p[j] = csr[idc];
            if (idx >= en) p[j].y = 0;
        }
        f16x8 v[4];
        #pragma unroll
        for (int j = 0; j < 4; ++j)
            v[j] = av[(size_t)p[j].x * 16 + l];
        #pragma unroll
        for (int j = 0; j < 4; ++j) {
            float w = __int_as_float(p[j].y);
            #pragma unroll
            for (int i = 0; i < 8; ++i) acc[i] += w * (float)v[j][i];
        }
    }

    #pragma unroll
    for (int i = 0; i < 8; ++i) {
        acc[i] += __shfl_xor(acc[i], 16, 64);
        acc[i] += __shfl_xor(acc[i], 32, 64);
    }

    float v[8];
    float s = 0.f, ss = 0.f;
    #pragma unroll
    for (int i = 0; i < 8; ++i) {
        v[i] = acc[i] + (float)dv[i];
        s += v[i]; ss += v[i] * v[i];
    }
    #pragma unroll
    for (int off = 1; off <= 8; off <<= 1) {
        s  += __shfl_xor(s,  off, 64);
        ss += __shfl_xor(ss, off, 64);
    }
    float mean = s * (1.f / 128.f);
    float var = ss * (1.f / 128.f) - mean * mean;
    float rstd = rsqrtf(var + 1e-5f);

    const float4* gv4 = (const float4*)g;
    const float4* bv4 = (const float4*)beta;
    float4 ga = gv4[l*2], gb = gv4[l*2+1];
    float4 ba = bv4[l*2], bb = bv4[l*2+1];
    float go[8] = {ga.x,ga.y,ga.z,ga.w,gb.x,gb.y,gb.z,gb.w};
    float bo[8] = {ba.x,ba.y,ba.z,ba.w,bb.x,bb.y,bb.z,bb.w};
    f16x8 ov;
    #pragma unroll
    for (int i = 0; i < 8; ++i) {
        float o = (v[i] - mean) * rstd * go[i] + bo[i];
        o = o >= 0.f ? o : 0.1f * o;
        ov[i] = (_Float16)o;
    }
    if (grp == 0)
        ((f16x8*)out)[(size_t)node * 16 + l] = ov;
}

// ===================== final aggregate + LN + leaky + output GEMV ==========

__global__ __launch_bounds__(256) void aggregate_out_kernel(
    const int* __restrict__ rowptr, const int2* __restrict__ csr,
    const _Float16* __restrict__ a, const _Float16* __restrict__ d,
    const float* __restrict__ g, const float* __restrict__ beta,
    const float* __restrict__ W1o, const float* __restrict__ b1o,
    const float* __restrict__ W2o,
    const float* __restrict__ W3o, const float* __restrict__ b3o,
    const float* __restrict__ wsum,
    float* __restrict__ a1, float* __restrict__ dpart, int N)
{
    int wave = threadIdx.x >> 6;
    int lane = threadIdx.x & 63;
    int grp  = lane >> 4;
    int l    = lane & 15;
    int node = blockIdx.x * 4 + wave;
    if (node >= N) return;
    int b = rowptr[node], en = rowptr[node + 1];
    int deg = en - b;

    const f16x8* av = (const f16x8*)a;
    f16x8 dv = ((const f16x8*)d)[(size_t)node * 16 + l];   // hoisted
    float wsn = wsum[node];
    float acc[8] = {0,0,0,0,0,0,0,0};

    int nk = (deg + 3) >> 2;
    int k = 0;
    for (; k + 4 <= nk; k += 4) {
        int2 p[4];
        #pragma unroll
        for (int j = 0; j < 4; ++j) {
            int idx = b + (k + j) * 4 + grp;
            int idc = (idx < en) ? idx : b;
            p[j] = csr[idc];
            if (idx >= en) p[j].y = 0;
        }
        f16x8 v[4];
        #pragma unroll
        for (int j = 0; j < 4; ++j)
            v[j] = av[(size_t)p[j].x * 16 + l];
        #pragma unroll
        for (int j = 0; j < 4; ++j) {
            float w = __int_as_float(p[j].y);
            #pragma unroll
            for (int i = 0; i < 8; ++i) acc[i] += w * (float)v[j][i];
        }
    }
    if (k < nk) {                        // predicated batch tail
        int2 p[4];
        #pragma unroll
        for (int j = 0; j < 4; ++j) {
            int idx = b + (k + j) * 4 + grp;
            int idc = (idx < en) ? idx : b;
            p[j] = csr[idc];
            if (idx >= en) p[j].y = 0;
        }
        f16x8 v[4];
        #pragma unroll
        for (int j = 0; j < 4; ++j)
            v[j] = av[(size_t)p[j].x * 16 + l];
        #pragma unroll
        for (int j = 0; j < 4; ++j) {
            float w = __int_as_float(p[j].y);
            #pragma unroll
            for (int i = 0; i < 8; ++i) acc[i] += w * (float)v[j][i];
        }
    }

    #pragma unroll
    for (int i = 0; i < 8; ++i) {
        acc[i] += __shfl_xor(acc[i], 16, 64);
        acc[i] += __shfl_xor(acc[i], 32, 64);
    }

    float v[8];
    float s = 0.f, ss = 0.f;
    #pragma unroll
    for (int i = 0; i < 8; ++i) {
        v[i] = acc[i] + (float)dv[i];
        s += v[i]; ss += v[i] * v[i];
    }
    #pragma unroll
    for (int off = 1; off <= 8; off <<= 1) {
        s  += __shfl_xor(s,  off, 64);
        ss += __shfl_xor(ss, off, 64);
    }
    float mean = s * (1.f / 128.f);
    float var = ss * (1.f / 128.f) - mean * mean;
    float rstd = rsqrtf(var + 1e-5f);

    const float4* gv4 = (const float4*)g;
    const float4* bv4 = (const float4*)beta;
    float4 ga = gv4[l*2], gb = gv4[l*2+1];
    float4 ba = bv4[l*2], bb = bv4[l*2+1];
    float go[8] = {ga.x,ga.y,ga.z,ga.w,gb.x,gb.y,gb.z,gb.w};
    float bo[8] = {ba.x,ba.y,ba.z,ba.w,bb.x,bb.y,bb.z,bb.w};

    // post-LN/leaky row element; round-trip through f16 to match the
    // two-kernel path bit-for-bit (out_gemv used to read f16 h).
    float ho[8];
    #pragma unroll
    for (int i = 0; i < 8; ++i) {
        float o = (v[i] - mean) * rstd * go[i] + bo[i];
        o = o >= 0.f ? o : 0.1f * o;
        ho[i] = (float)(_Float16)o;
    }

    // three dot products over the 128-row: lane l holds cols 8l..8l+7
    const float4* w1v = (const float4*)W1o;
    const float4* w2v = (const float4*)W2o;
    const float4* w3v = (const float4*)W3o;
    float4 w1a = w1v[l*2], w1b = w1v[l*2+1];
    float4 w2a = w2v[l*2], w2b = w2v[l*2+1];
    float4 w3a = w3v[l*2], w3b = w3v[l*2+1];
    float s1 = ho[0]*w1a.x + ho[1]*w1a.y + ho[2]*w1a.z + ho[3]*w1a.w
             + ho[4]*w1b.x + ho[5]*w1b.y + ho[6]*w1b.z + ho[7]*w1b.w;
    float s2 = ho[0]*w2a.x + ho[1]*w2a.y + ho[2]*w2a.z + ho[3]*w2a.w
             + ho[4]*w2b.x + ho[5]*w2b.y + ho[6]*w2b.z + ho[7]*w2b.w;
    float s3 = ho[0]*w3a.x + ho[1]*w3a.y + ho[2]*w3a.z + ho[3]*w3a.w
             + ho[4]*w3b.x + ho[5]*w3b.y + ho[6]*w3b.z + ho[7]*w3b.w;
    #pragma unroll
    for (int off = 1; off <= 8; off <<= 1) {
        s1 += __shfl_xor(s1, off, 64);
        s2 += __shfl_xor(s2, off, 64);
        s3 += __shfl_xor(s3, off, 64);
    }
    if (lane == 0) {
        a1[node] = s1 + b1o[0];
        dpart[node] = s3 + b3o[0] - wsn * s2;
    }
}

// ===================== output gather + sigmoid =====================

__global__ __launch_bounds__(256) void gather_out_kernel(
    const int* __restrict__ rowptr, const int2* __restrict__ csr,
    const float* __restrict__ a1, const float* __restrict__ dpart,
    float* __restrict__ out, int N)
{
    int n = blockIdx.x * 256 + threadIdx.x;
    if (n >= N) return;
    int b = rowptr[n], en = rowptr[n + 1];
    float s = dpart[n];
    int e = b;
    for (; e + 4 <= en; e += 4) {
        int2 p0 = csr[e], p1 = csr[e+1], p2 = csr[e+2], p3 = csr[e+3];
        float x0 = a1[p0.x], x1 = a1[p1.x], x2 = a1[p2.x], x3 = a1[p3.x];
        s += __int_as_float(p0.y) * x0 + __int_as_float(p1.y) * x1
           + __int_as_float(p2.y) * x2 + __int_as_float(p3.y) * x3;
    }
    for (; e < en; ++e) {
        int2 p = csr[e];
        s += __int_as_float(p.y) * a1[p.x];
    }
    out[n] = 1.f / (1.f + expf(-s));
}

// ---------------------------------------------------------------------------
extern "C" void kernel_launch(void* const* d_in, const int* in_sizes, int n_in,
                              void* d_out, int out_size, void* d_ws, size_t ws_size,
                              hipStream_t stream)
{
    const float* x     = (const float*)d_in[0];
    const float* ew    = (const float*)d_in[1];
    const float* W1_in = (const float*)d_in[2];
    const float* b1_in = (const float*)d_in[3];
    const float* W2_in = (const float*)d_in[4];
    const float* W3_in = (const float*)d_in[5];
    const float* b3_in = (const float*)d_in[6];
    const float* W1_h  = (const float*)d_in[7];
    const float* b1_h  = (const float*)d_in[8];
    const float* W2_h  = (const float*)d_in[9];
    const float* W3_h  = (const float*)d_in[10];
    const float* b3_h  = (const float*)d_in[11];
    const float* W1_o  = (const float*)d_in[12];
    const float* b1_o  = (const float*)d_in[13];
    const float* W2_o  = (const float*)d_in[14];
    const float* W3_o  = (const float*)d_in[15];
    const float* b3_o  = (const float*)d_in[16];
    const float* g1    = (const float*)d_in[17];
    const float* beta1 = (const float*)d_in[18];
    const float* g2    = (const float*)d_in[19];
    const float* beta2 = (const float*)d_in[20];
    const int*   eidx  = (const int*)d_in[21];

    const int N = in_sizes[0] / 128;
    const int E = in_sizes[1];
    const int* srcp = eidx;
    const int* dstp = eidx + E;

    // ---- workspace carve-out (256B-aligned chunks) ----
    size_t off = 0;
    auto carve = [&](size_t nbytes) -> void* {
        void* p = (char*)d_ws + off;
        off += (nbytes + 255) & ~(size_t)255;
        return p;
    };
    unsigned long long* degw = (unsigned long long*)carve((size_t)N * 8);
    int*      rank   = (int*)     carve((size_t)E * 4);
    _Float16* buf_h  = (_Float16*)carve((size_t)N * 128 * 2);
    _Float16* buf_a  = (_Float16*)carve((size_t)N * 128 * 2);
    _Float16* buf_d  = (_Float16*)carve((size_t)N * 128 * 2);
    int2*     csr    = (int2*)    carve((size_t)E * 8);
    _Float16* Wt_in  = (_Float16*)carve(384 * 128 * 2);
    _Float16* Wt_h   = (_Float16*)carve(384 * 128 * 2);
    int*      rowptr = (int*)     carve((size_t)(N + 1) * 4);
    int*      partial= (int*)     carve(256 * 4);
    int*      counter= (int*)     carve(256 * 4);
    float*    ps     = (float*)   carve((size_t)CS_BLOCKS * 128 * 4);
    float*    pss    = (float*)   carve((size_t)CS_BLOCKS * 128 * 4);
    float*    meanp  = (float*)   carve(128 * 4);
    float*    rstdp  = (float*)   carve(128 * 4);
    float*    wsum   = (float*)   carve((size_t)N * 4);
    float*    a1     = (float*)   carve((size_t)N * 4);
    float*    dpart  = (float*)   carve((size_t)N * 4);

    const int nodeWaveBlocks = (N + 3) / 4;
    const int eBlocks = (E + 255) / 256;
    const int nBlocks = (N + 255) / 256;
    const int nb = (N + 1023) / 1024;
    const int nTiles = (N + 63) / 64;
    const int gemmGrid = (nTiles < 512) ? nTiles : 512;   // proven best

    // ---- 1. prep: zero degw/counters (tiny) ----
    prep_zero_kernel<<<128, 256, 0, stream>>>(N, degw, counter);

    // ---- 2. colstats + weight-convert + packed histogram (co-scheduled) ----
    hist_cs_kernel<<<CS_BLOCKS + 384 + eBlocks, 256, 0, stream>>>(
        dstp, ew, degw, rank, E, x, N, ps, pss,
        W1_in, W2_in, W3_in, Wt_in, W1_h, W2_h, W3_h, Wt_h);

    // ---- 3. fused scan + column-stats reduction (co-scheduled) ----
    scan_stats_kernel<<<nb + 128, 256, 0, stream>>>(
        degw, N, wsum, rowptr, E, partial, counter, nb,
        ps, pss, meanp, rstdp);

    // ---- 4. CSR fill + GEMM layer 1 (co-scheduled) ----
    fill_gemm1_kernel<<<eBlocks + gemmGrid, 256, 0, stream>>>(
        srcp, dstp, ew, rowptr, rank, csr, E, eBlocks,
        x, meanp, rstdp, N, nTiles, gemmGrid,
        Wt_in, b1_in, b3_in, wsum, buf_a, buf_d);

    // ---- 5. aggregate L1 ----
    aggregate_ln_kernel<<<nodeWaveBlocks, 256, 0, stream>>>(rowptr, csr, buf_a, buf_d, g1, beta1, buf_h, N);

    // ---- 6-7. layer 2 ----
    gemm_mfma_kernel<<<gemmGrid, 256, 0, stream>>>(buf_h, N, nTiles, Wt_h, b1_h, b3_h, wsum, buf_a, buf_d);
    aggregate_ln_kernel<<<nodeWaveBlocks, 256, 0, stream>>>(rowptr, csr, buf_a, buf_d, g2, beta2, buf_h, N);

    // ---- 8-9. layer 3 + output GEMV fused into the final aggregate ----
    gemm_mfma_kernel<<<gemmGrid, 256, 0, stream>>>(buf_h, N, nTiles, Wt_h, b1_h, b3_h, wsum, buf_a, buf_d);
    aggregate_out_kernel<<<nodeWaveBlocks, 256, 0, stream>>>(
        rowptr, csr, buf_a, buf_d, g2, beta2,
        W1_o, b1_o, W2_o, W3_o, b3_o, wsum, a1, dpart, N);

    // ---- 10. output gather + sigmoid ----
    gather_out_kernel<<<nBlocks, 256, 0, stream>>>(rowptr, csr, a1, dpart, (float*)d_out, N);
}